// Round 8
// baseline (204.120 us; speedup 1.0000x reference)
//
#include <hip/hip_runtime.h>

#define NF 128   // in/hidden features
#define NC 64    // classes
#define SLICES 64

typedef short bf16x8 __attribute__((ext_vector_type(8)));
typedef float f32x4 __attribute__((ext_vector_type(4)));

__device__ __forceinline__ unsigned f2bf(float f) {   // fp32 -> bf16 (RTN)
    unsigned u = __float_as_uint(f);
    return (u + 0x7FFFu + ((u >> 16) & 1u)) >> 16;
}
__device__ __forceinline__ float bf2f(unsigned h) { return __uint_as_float(h << 16); }

// ---- one-time: Wt1[n][k] = bf16(W1[k][n]), Wt2[n][k] = bf16(W2[k][n]) ----
__global__ __launch_bounds__(256) void wt_prep(const float* __restrict__ W1,
                                               const float* __restrict__ W2,
                                               unsigned short* __restrict__ Wt1,
                                               unsigned short* __restrict__ Wt2) {
    int i = blockIdx.x * 256 + threadIdx.x;
    if (i < 128 * 128) {
        int k = i >> 7, n = i & 127;
        Wt1[n * 128 + k] = (unsigned short)f2bf(W1[i]);
    } else {
        int j = i - 128 * 128;
        if (j < 128 * 64) {
            int k = j >> 6, n = j & 63;
            Wt2[n * 128 + k] = (unsigned short)f2bf(W2[j]);
        }
    }
}

// ---- LDS-privatized count+rank: 2 node-halves x SLICES edge-slices ----
__global__ __launch_bounds__(256) void count_rank_kernel(const int* __restrict__ col,
                                                         unsigned short* __restrict__ eoff16,
                                                         unsigned short* __restrict__ C16,
                                                         int N, int E, int SL, int nh) {
    __shared__ unsigned hist[12544];
    const int j = blockIdx.x >> 1;   // slice
    const int h = blockIdx.x & 1;    // node half
    const int nlo = h * nh;
    const int nhi = min(N, nlo + nh);
    const int words = (nhi - nlo + 1) >> 1;
    for (int i = threadIdx.x; i < words; i += 256) hist[i] = 0;
    __syncthreads();
    const int e0 = j * SL, e1 = min(E, e0 + SL);
    for (int e = e0 + threadIdx.x; e < e1; e += 256) {
        int c = col[e];
        if (c >= nlo && c < nhi) {
            int cl = c - nlo;
            unsigned sh = (cl & 1) * 16;
            unsigned old = atomicAdd(&hist[cl >> 1], 1u << sh);
            eoff16[e] = (unsigned short)((old >> sh) & 0xffffu);
        }
    }
    __syncthreads();
    unsigned* Cw = (unsigned*)(C16 + (size_t)j * N + nlo);
    for (int i = threadIdx.x; i < words; i += 256) Cw[i] = hist[i];
}

// ---- per-node exclusive scan over slices (in place) + totals ----
__global__ __launch_bounds__(256) void scanC_kernel(unsigned short* __restrict__ C16,
                                                    int* __restrict__ tot, int N) {
    int n = blockIdx.x * 256 + threadIdx.x;
    if (n >= N) return;
    int t = 0;
#pragma unroll 4
    for (int j = 0; j < SLICES; ++j) {
        size_t idx = (size_t)j * N + n;
        int v = C16[idx];
        C16[idx] = (unsigned short)t;
        t += v;
    }
    tot[n] = t;
}

// ---- exclusive scan of tot[N] -> rowPtr[N+1] ----
__global__ __launch_bounds__(256) void scan_blocks(const int* __restrict__ cnt,
                                                   int* __restrict__ excl,
                                                   int* __restrict__ bsum, int N) {
    __shared__ int sh[256];
    int t = threadIdx.x;
    int base = blockIdx.x * 1024 + t * 4;
    int v0 = base + 0 < N ? cnt[base + 0] : 0;
    int v1 = base + 1 < N ? cnt[base + 1] : 0;
    int v2 = base + 2 < N ? cnt[base + 2] : 0;
    int v3 = base + 3 < N ? cnt[base + 3] : 0;
    int s = v0 + v1 + v2 + v3;
    sh[t] = s;
    __syncthreads();
    for (int off = 1; off < 256; off <<= 1) {
        int x = (t >= off) ? sh[t - off] : 0;
        __syncthreads();
        sh[t] += x;
        __syncthreads();
    }
    int incl = sh[t];
    int exclT = incl - s;
    if (t == 255) bsum[blockIdx.x] = incl;
    if (base + 0 < N) excl[base + 0] = exclT;
    if (base + 1 < N) excl[base + 1] = exclT + v0;
    if (base + 2 < N) excl[base + 2] = exclT + v0 + v1;
    if (base + 3 < N) excl[base + 3] = exclT + v0 + v1 + v2;
}

__global__ void scan_sums(int* __restrict__ bsum, int nb) {
    int run = 0;
    for (int i = 0; i < nb; ++i) { int v = bsum[i]; bsum[i] = run; run += v; }
    bsum[nb] = run;
}

__global__ __launch_bounds__(256) void scan_add(int* __restrict__ excl,
                                                const int* __restrict__ bsum,
                                                int N, int nb) {
    int i = blockIdx.x * 256 + threadIdx.x;
    if (i < N) excl[i] += bsum[i >> 10];
    if (i == 0) excl[N] = bsum[nb];
}

// ---- fused: quarter-partitioned scatter (no atomics) + MFMA gemm1 (H1=X@W1, bf16) ----
__global__ __launch_bounds__(256) void scatter_gemm1_fused(const int* __restrict__ row,
                                                           const int* __restrict__ col,
                                                           const float* __restrict__ ew,
                                                           const int* __restrict__ rowPtr,
                                                           const unsigned short* __restrict__ Coff16,
                                                           const unsigned short* __restrict__ eoff16,
                                                           int2* __restrict__ csr,
                                                           const float* __restrict__ X,
                                                           const unsigned short* __restrict__ Wt1,
                                                           unsigned short* __restrict__ H,
                                                           int N, int E, int SL, int SB, int nq) {
    __shared__ char XsB[32768];   // 128 rows x 128 k bf16, XOR-swizzled
    __shared__ char WsB[32768];   // 128 n   x 128 k bf16, XOR-swizzled
    if ((int)blockIdx.x < SB) {
        int q = blockIdx.x & 3;
        int qlo = q * nq, qhi = min(N, qlo + nq);
        int stride = (SB >> 2) * 256;
        for (int e = (blockIdx.x >> 2) * 256 + threadIdx.x; e < E; e += stride) {
            int c = col[e];
            if (c < qlo || c >= qhi) continue;
            int j = e / SL;
            int idx = rowPtr[c] + (int)Coff16[(size_t)j * N + c] + (int)eoff16[e];
            csr[idx] = make_int2(row[e], __float_as_int(ew[e]));
        }
        return;
    }
    const int tid = threadIdx.x;
    const int bm0 = ((int)blockIdx.x - SB) * 128;
    {   // stage X -> bf16, swizzled; coalesced: 2 full rows per wave pass
        int k4 = tid & 31;          // float4 index in row
        int r0 = tid >> 5;
        for (int it = 0; it < 16; ++it) {
            int r = it * 8 + r0;
            int node = min(bm0 + r, N - 1);
            float4 v = *(const float4*)(X + (size_t)node * 128 + k4 * 4);
            unsigned lo = f2bf(v.x) | (f2bf(v.y) << 16);
            unsigned hi = f2bf(v.z) | (f2bf(v.w) << 16);
            int byte = r * 256 + ((k4 * 8) ^ ((r & 7) << 4));
            *(uint2*)(XsB + byte) = make_uint2(lo, hi);
        }
    }
    {   // stage Wt1 (already bf16) swizzled
        const uint4* src = (const uint4*)Wt1;
        for (int t = 0; t < 8; ++t) {
            int i = t * 256 + tid;  // 2048 uint4
            int n = i >> 4, kb = (i & 15) * 16;
            *(uint4*)(WsB + n * 256 + (kb ^ ((n & 7) << 4))) = src[i];
        }
    }
    __syncthreads();
    const int w = tid >> 6, l = tid & 63;
    const int lr = l & 15, lg = l >> 4;
    f32x4 acc[2][8] = {};
#pragma unroll
    for (int kk = 0; kk < 4; ++kk) {
        bf16x8 a[2], b[8];
#pragma unroll
        for (int mt = 0; mt < 2; ++mt) {
            int r = w * 32 + mt * 16 + lr;
            a[mt] = *(const bf16x8*)(XsB + r * 256 + ((kk * 64 + lg * 16) ^ ((r & 7) << 4)));
        }
#pragma unroll
        for (int nt = 0; nt < 8; ++nt) {
            int n = nt * 16 + lr;
            b[nt] = *(const bf16x8*)(WsB + n * 256 + ((kk * 64 + lg * 16) ^ ((n & 7) << 4)));
        }
#pragma unroll
        for (int mt = 0; mt < 2; ++mt)
#pragma unroll
            for (int nt = 0; nt < 8; ++nt)
                acc[mt][nt] = __builtin_amdgcn_mfma_f32_16x16x32_bf16(a[mt], b[nt], acc[mt][nt], 0, 0, 0);
    }
#pragma unroll
    for (int mt = 0; mt < 2; ++mt)
#pragma unroll
        for (int reg = 0; reg < 4; ++reg) {
            int node = bm0 + w * 32 + mt * 16 + lg * 4 + reg;
            if (node < N) {
#pragma unroll
                for (int nt = 0; nt < 8; ++nt)
                    H[(size_t)node * 128 + nt * 16 + lr] = (unsigned short)f2bf(acc[mt][nt][reg]);
            }
        }
}

// ---- MFMA gemm2: H3[N x 64 bf16] = A(bf16 [N][128]) @ W2 ----
__global__ __launch_bounds__(256) void gemm2_mfma(const unsigned short* __restrict__ A,
                                                  const unsigned short* __restrict__ Wt2,
                                                  unsigned short* __restrict__ H, int N) {
    __shared__ char XsB[32768];   // 128 rows x 128 k bf16, swizzled
    __shared__ char WsB[16384];   // 64 n x 128 k bf16, swizzled
    const int tid = threadIdx.x;
    const int bm0 = blockIdx.x * 128;
    {   // stage A rows (bf16): 16 rows/pass, 8 passes
        int k16 = tid & 15, r0 = tid >> 4;
        for (int it = 0; it < 8; ++it) {
            int r = it * 16 + r0;
            int node = min(bm0 + r, N - 1);
            uint4 g = *(const uint4*)(A + (size_t)node * 128 + k16 * 8);
            *(uint4*)(XsB + r * 256 + ((k16 * 16) ^ ((r & 7) << 4))) = g;
        }
    }
    {   // stage Wt2: 1024 uint4
        const uint4* src = (const uint4*)Wt2;
        for (int t = 0; t < 4; ++t) {
            int i = t * 256 + tid;
            int n = i >> 4, kb = (i & 15) * 16;
            *(uint4*)(WsB + n * 256 + (kb ^ ((n & 7) << 4))) = src[i];
        }
    }
    __syncthreads();
    const int w = tid >> 6, l = tid & 63;
    const int lr = l & 15, lg = l >> 4;
    f32x4 acc[2][4] = {};
#pragma unroll
    for (int kk = 0; kk < 4; ++kk) {
        bf16x8 a[2], b[4];
#pragma unroll
        for (int mt = 0; mt < 2; ++mt) {
            int r = w * 32 + mt * 16 + lr;
            a[mt] = *(const bf16x8*)(XsB + r * 256 + ((kk * 64 + lg * 16) ^ ((r & 7) << 4)));
        }
#pragma unroll
        for (int nt = 0; nt < 4; ++nt) {
            int n = nt * 16 + lr;
            b[nt] = *(const bf16x8*)(WsB + n * 256 + ((kk * 64 + lg * 16) ^ ((n & 7) << 4)));
        }
#pragma unroll
        for (int mt = 0; mt < 2; ++mt)
#pragma unroll
            for (int nt = 0; nt < 4; ++nt)
                acc[mt][nt] = __builtin_amdgcn_mfma_f32_16x16x32_bf16(a[mt], b[nt], acc[mt][nt], 0, 0, 0);
    }
#pragma unroll
    for (int mt = 0; mt < 2; ++mt)
#pragma unroll
        for (int reg = 0; reg < 4; ++reg) {
            int node = bm0 + w * 32 + mt * 16 + lg * 4 + reg;
            if (node < N) {
#pragma unroll
                for (int nt = 0; nt < 4; ++nt)
                    H[(size_t)node * 64 + nt * 16 + lr] = (unsigned short)f2bf(acc[mt][nt][reg]);
            }
        }
}

// ---- deg from CSR segment sum; dinv = rsqrt(deg + 1). 16 lanes per node ----
__global__ __launch_bounds__(256) void deg_dinv_kernel(const int* __restrict__ rowPtr,
                                                       const int2* __restrict__ csr,
                                                       float* __restrict__ dinv, int N) {
    int idx = blockIdx.x * 256 + threadIdx.x;
    int n = idx >> 4, l = idx & 15;
    if (n >= N) return;
    int beg = rowPtr[n], end = rowPtr[n + 1];
    float s = 0.f;
    for (int i = beg + l; i < end; i += 16) s += __int_as_float(csr[i].y);
#pragma unroll
    for (int off = 8; off; off >>= 1) s += __shfl_xor(s, off, 16);
    if (l == 0) dinv[n] = rsqrtf(s + 1.0f);
}

// ---- layer 1 gather (bf16 H1) + on-fly normalize + self + bias + relu -> bf16 out ----
__global__ __launch_bounds__(256) void agg_gather1(const int* __restrict__ rowPtr,
                                                   const int2* __restrict__ csr,   // (src, raw ew)
                                                   const unsigned* __restrict__ H1u,  // [N][64] bf16x2
                                                   const float* __restrict__ dinv,
                                                   const float2* __restrict__ b2,
                                                   unsigned* __restrict__ out1, int N) {
    int n = (blockIdx.x * 256 + threadIdx.x) >> 6;
    int lane = threadIdx.x & 63;
    if (n >= N) return;
    float dn = dinv[n];
    float accx = 0.f, accy = 0.f;
    int beg = rowPtr[n], end = rowPtr[n + 1];
    int j = beg;
    for (; j + 4 <= end; j += 4) {
        int2 p0 = csr[j + 0], p1 = csr[j + 1], p2 = csr[j + 2], p3 = csr[j + 3];
        float w0 = __int_as_float(p0.y) * dinv[p0.x];
        float w1 = __int_as_float(p1.y) * dinv[p1.x];
        float w2 = __int_as_float(p2.y) * dinv[p2.x];
        float w3 = __int_as_float(p3.y) * dinv[p3.x];
        unsigned v0 = H1u[(size_t)p0.x * 64 + lane];
        unsigned v1 = H1u[(size_t)p1.x * 64 + lane];
        unsigned v2 = H1u[(size_t)p2.x * 64 + lane];
        unsigned v3 = H1u[(size_t)p3.x * 64 + lane];
        accx += w0 * bf2f(v0 & 0xffffu); accy += w0 * bf2f(v0 >> 16);
        accx += w1 * bf2f(v1 & 0xffffu); accy += w1 * bf2f(v1 >> 16);
        accx += w2 * bf2f(v2 & 0xffffu); accy += w2 * bf2f(v2 >> 16);
        accx += w3 * bf2f(v3 & 0xffffu); accy += w3 * bf2f(v3 >> 16);
    }
    for (; j < end; ++j) {
        int2 p = csr[j];
        float w = __int_as_float(p.y) * dinv[p.x];
        unsigned v = H1u[(size_t)p.x * 64 + lane];
        accx += w * bf2f(v & 0xffffu); accy += w * bf2f(v >> 16);
    }
    unsigned hv = H1u[(size_t)n * 64 + lane];
    float2 bb = b2[lane];
    float s = dn * dn;
    float ox = fmaxf(fmaf(dn, accx, s * bf2f(hv & 0xffffu)) + bb.x, 0.f);
    float oy = fmaxf(fmaf(dn, accy, s * bf2f(hv >> 16)) + bb.y, 0.f);
    out1[(size_t)n * 64 + lane] = f2bf(ox) | (f2bf(oy) << 16);
}

// ---- layer 2 gather (bf16 H3) + on-fly normalize + self + bias + L2 norm ----
__global__ __launch_bounds__(256) void agg_gather2(const int* __restrict__ rowPtr,
                                                   const int2* __restrict__ csr,
                                                   const unsigned* __restrict__ H3u,  // [N][32] bf16x2
                                                   const float* __restrict__ dinv,
                                                   const float2* __restrict__ b2,
                                                   float2* __restrict__ out2, int N) {
    int n = (blockIdx.x * 256 + threadIdx.x) >> 5;
    int l = threadIdx.x & 31;
    if (n >= N) return;
    float dn = dinv[n];
    float accx = 0.f, accy = 0.f;
    int beg = rowPtr[n], end = rowPtr[n + 1];
    int j = beg;
    for (; j + 4 <= end; j += 4) {
        int2 p0 = csr[j + 0], p1 = csr[j + 1], p2 = csr[j + 2], p3 = csr[j + 3];
        float w0 = __int_as_float(p0.y) * dinv[p0.x];
        float w1 = __int_as_float(p1.y) * dinv[p1.x];
        float w2 = __int_as_float(p2.y) * dinv[p2.x];
        float w3 = __int_as_float(p3.y) * dinv[p3.x];
        unsigned v0 = H3u[(size_t)p0.x * 32 + l];
        unsigned v1 = H3u[(size_t)p1.x * 32 + l];
        unsigned v2 = H3u[(size_t)p2.x * 32 + l];
        unsigned v3 = H3u[(size_t)p3.x * 32 + l];
        accx += w0 * bf2f(v0 & 0xffffu); accy += w0 * bf2f(v0 >> 16);
        accx += w1 * bf2f(v1 & 0xffffu); accy += w1 * bf2f(v1 >> 16);
        accx += w2 * bf2f(v2 & 0xffffu); accy += w2 * bf2f(v2 >> 16);
        accx += w3 * bf2f(v3 & 0xffffu); accy += w3 * bf2f(v3 >> 16);
    }
    for (; j < end; ++j) {
        int2 p = csr[j];
        float w = __int_as_float(p.y) * dinv[p.x];
        unsigned v = H3u[(size_t)p.x * 32 + l];
        accx += w * bf2f(v & 0xffffu); accy += w * bf2f(v >> 16);
    }
    unsigned hv = H3u[(size_t)n * 32 + l];
    float2 bb = b2[l];
    float s = dn * dn;
    float vx = fmaf(dn, accx, s * bf2f(hv & 0xffffu)) + bb.x;
    float vy = fmaf(dn, accy, s * bf2f(hv >> 16)) + bb.y;
    float ss = vx * vx + vy * vy;
#pragma unroll
    for (int off = 16; off; off >>= 1) ss += __shfl_xor(ss, off, 64);  // stays in 32-group
    float scale = 1.0f / fmaxf(sqrtf(ss), 1e-12f);
    out2[(size_t)n * 32 + l] = make_float2(vx * scale, vy * scale);
}

extern "C" void kernel_launch(void* const* d_in, const int* in_sizes, int n_in,
                              void* d_out, int out_size, void* d_ws, size_t ws_size,
                              hipStream_t stream) {
    const float* x  = (const float*)d_in[0];
    const int*   ei = (const int*)d_in[1];
    const float* ew = (const float*)d_in[2];
    const float* W1 = (const float*)d_in[3];
    const float* b1 = (const float*)d_in[4];
    const float* W2 = (const float*)d_in[5];
    const float* b2 = (const float*)d_in[6];
    float* out = (float*)d_out;
    const int N = in_sizes[0] / NF;
    const int E = in_sizes[2];
    const int* row = ei;
    const int* col = ei + E;
    const int NB = (N + 1023) / 1024;
    const int SL = (E + SLICES - 1) / SLICES;
    const int nh = (N + 1) / 2;
    const int nq = (N + 3) / 4;

    char* ws = (char*)d_ws;
    size_t off = 0;
    auto take = [&](size_t bytes) {
        char* p = ws + off;
        off = (off + bytes + 255) & ~(size_t)255;
        return p;
    };
    float* dinv   = (float*)take((size_t)N * 4);
    int*   tot    = (int*)  take((size_t)N * 4);
    int*   rowPtr = (int*)  take((size_t)(N + 1) * 4);
    unsigned short* eoff16 = (unsigned short*)take((size_t)E * 2);
    int*   bsum   = (int*)  take((size_t)(NB + 1) * 4);
    unsigned short* C16    = (unsigned short*)take((size_t)SLICES * N * 2);
    int2*  csr    = (int2*) take((size_t)E * 8);
    unsigned short* H1   = (unsigned short*)take((size_t)N * NF * 2);  // bf16; reused as H3
    unsigned short* relu = (unsigned short*)take((size_t)N * NF * 2);  // bf16
    unsigned short* Wt1  = (unsigned short*)take(128 * 128 * 2);
    unsigned short* Wt2  = (unsigned short*)take(64 * 128 * 2);
    unsigned short* H3 = H1;   // [N][64] bf16, written after H1 consumed

    // weight transpose+cast (independent)
    wt_prep<<<96, 256, 0, stream>>>(W1, W2, Wt1, Wt2);

    // count + per-(slice,node) ranks — all atomics confined to LDS
    count_rank_kernel<<<2 * SLICES, 256, 0, stream>>>(col, eoff16, C16, N, E, SL, nh);
    scanC_kernel<<<(N + 255) / 256, 256, 0, stream>>>(C16, tot, N);
    scan_blocks<<<NB, 256, 0, stream>>>(tot, rowPtr, bsum, N);
    scan_sums<<<1, 1, 0, stream>>>(bsum, NB);
    scan_add<<<(N + 255) / 256, 256, 0, stream>>>(rowPtr, bsum, N, NB);

    // fused: quarter-partitioned CSR scatter || MFMA GEMM1
    const int SB = 128;
    const int GB = (N + 127) / 128;
    scatter_gemm1_fused<<<SB + GB, 256, 0, stream>>>(row, col, ew, rowPtr, C16, eoff16,
                                                     csr, x, Wt1, H1, N, E, SL, SB, nq);

    // degree -> dinv (weights normalized on the fly in agg kernels)
    deg_dinv_kernel<<<(N * 16 + 255) / 256, 256, 0, stream>>>(rowPtr, csr, dinv, N);

    // layer 1 aggregation + bias + relu -> bf16
    agg_gather1<<<(N * 64 + 255) / 256, 256, 0, stream>>>(rowPtr, csr, (const unsigned*)H1,
                                                          dinv, (const float2*)b1,
                                                          (unsigned*)relu, N);

    // layer 2: MFMA GEMM ; gather + bias + l2norm
    gemm2_mfma<<<(N + 127) / 128, 256, 0, stream>>>(relu, Wt2, H3, N);
    agg_gather2<<<(N * 32 + 255) / 256, 256, 0, stream>>>(rowPtr, csr, (const unsigned*)H3,
                                                          dinv, (const float2*)b2,
                                                          (float2*)out, N);
}

// Round 9
// 160.220 us; speedup vs baseline: 1.2740x; 1.2740x over previous
//
#include <hip/hip_runtime.h>

#define NF 128   // in/hidden features
#define NC 64    // classes
#define SLICES 64

typedef short bf16x8 __attribute__((ext_vector_type(8)));
typedef float f32x4 __attribute__((ext_vector_type(4)));

__device__ __forceinline__ unsigned f2bf(float f) {   // fp32 -> bf16 (RTN)
    unsigned u = __float_as_uint(f);
    return (u + 0x7FFFu + ((u >> 16) & 1u)) >> 16;
}
__device__ __forceinline__ float bf2f(unsigned h) { return __uint_as_float(h << 16); }

// ---- fused prep: count_rank blocks + weight-transpose blocks + X->bf16 cast blocks ----
__global__ __launch_bounds__(256) void prep_fused(const int* __restrict__ col,
                                                  unsigned short* __restrict__ eoff16,
                                                  unsigned short* __restrict__ C16,
                                                  const float* __restrict__ W1,
                                                  const float* __restrict__ W2,
                                                  unsigned short* __restrict__ Wt1,
                                                  unsigned short* __restrict__ Wt2,
                                                  const float* __restrict__ X,
                                                  unsigned* __restrict__ Xb2,   // [N*64] bf16x2
                                                  int N, int E, int SL, int nh,
                                                  int CRB, int WTB, int XCB) {
    __shared__ unsigned hist[12544];
    const int b = blockIdx.x;
    const int tid = threadIdx.x;
    if (b < CRB) {
        // ---- count + rank (LDS-private histogram, 2 packed 16-bit counters/word) ----
        const int j = b >> 1;
        const int h = b & 1;
        const int nlo = h * nh;
        const int nhi = min(N, nlo + nh);
        const int words = (nhi - nlo + 1) >> 1;
        for (int i = tid; i < words; i += 256) hist[i] = 0;
        __syncthreads();
        const int e0 = j * SL, e1 = min(E, e0 + SL);
        for (int e = e0 + tid; e < e1; e += 256) {
            int c = col[e];
            if (c >= nlo && c < nhi) {
                int cl = c - nlo;
                unsigned sh = (cl & 1) * 16;
                unsigned old = atomicAdd(&hist[cl >> 1], 1u << sh);
                eoff16[e] = (unsigned short)((old >> sh) & 0xffffu);
            }
        }
        __syncthreads();
        unsigned* Cw = (unsigned*)(C16 + (size_t)j * N + nlo);
        for (int i = tid; i < words; i += 256) Cw[i] = hist[i];
    } else if (b < CRB + WTB) {
        // ---- weight transpose + bf16 cast ----
        int i = (b - CRB) * 256 + tid;
        if (i < 128 * 128) {
            int k = i >> 7, n = i & 127;
            Wt1[n * 128 + k] = (unsigned short)f2bf(W1[i]);
        } else {
            int j = i - 128 * 128;
            if (j < 128 * 64) {
                int k = j >> 6, n = j & 63;
                Wt2[n * 128 + k] = (unsigned short)f2bf(W2[j]);
            }
        }
    } else {
        // ---- X -> bf16 streaming cast ----
        const float4* X4 = (const float4*)X;
        uint2* O = (uint2*)Xb2;
        int items = N * 32;
        for (int i = (b - CRB - WTB) * 256 + tid; i < items; i += XCB * 256) {
            float4 v = X4[i];
            O[i] = make_uint2(f2bf(v.x) | (f2bf(v.y) << 16),
                              f2bf(v.z) | (f2bf(v.w) << 16));
        }
    }
}

// ---- per-node exclusive scan over slices (in place) + totals ----
__global__ __launch_bounds__(256) void scanC_kernel(unsigned short* __restrict__ C16,
                                                    int* __restrict__ tot, int N) {
    int n = blockIdx.x * 256 + threadIdx.x;
    if (n >= N) return;
    int t = 0;
#pragma unroll 4
    for (int j = 0; j < SLICES; ++j) {
        size_t idx = (size_t)j * N + n;
        int v = C16[idx];
        C16[idx] = (unsigned short)t;
        t += v;
    }
    tot[n] = t;
}

// ---- exclusive scan of tot[N] -> rowPtr[N+1] ----
__global__ __launch_bounds__(256) void scan_blocks(const int* __restrict__ cnt,
                                                   int* __restrict__ excl,
                                                   int* __restrict__ bsum, int N) {
    __shared__ int sh[256];
    int t = threadIdx.x;
    int base = blockIdx.x * 1024 + t * 4;
    int v0 = base + 0 < N ? cnt[base + 0] : 0;
    int v1 = base + 1 < N ? cnt[base + 1] : 0;
    int v2 = base + 2 < N ? cnt[base + 2] : 0;
    int v3 = base + 3 < N ? cnt[base + 3] : 0;
    int s = v0 + v1 + v2 + v3;
    sh[t] = s;
    __syncthreads();
    for (int off = 1; off < 256; off <<= 1) {
        int x = (t >= off) ? sh[t - off] : 0;
        __syncthreads();
        sh[t] += x;
        __syncthreads();
    }
    int incl = sh[t];
    int exclT = incl - s;
    if (t == 255) bsum[blockIdx.x] = incl;
    if (base + 0 < N) excl[base + 0] = exclT;
    if (base + 1 < N) excl[base + 1] = exclT + v0;
    if (base + 2 < N) excl[base + 2] = exclT + v0 + v1;
    if (base + 3 < N) excl[base + 3] = exclT + v0 + v1 + v2;
}

__global__ void scan_sums(int* __restrict__ bsum, int nb) {
    int run = 0;
    for (int i = 0; i < nb; ++i) { int v = bsum[i]; bsum[i] = run; run += v; }
    bsum[nb] = run;
}

__global__ __launch_bounds__(256) void scan_add(int* __restrict__ excl,
                                                const int* __restrict__ bsum,
                                                int N, int nb) {
    int i = blockIdx.x * 256 + threadIdx.x;
    if (i < N) excl[i] += bsum[i >> 10];
    if (i == 0) excl[N] = bsum[nb];
}

// ---- fused: slice-aligned scatter (no atomics, contiguous reads) + MFMA gemm1 ----
__global__ __launch_bounds__(256) void scatter_gemm1_fused(const int* __restrict__ row,
                                                           const int* __restrict__ col,
                                                           const float* __restrict__ ew,
                                                           const int* __restrict__ rowPtr,
                                                           const unsigned short* __restrict__ Coff16,
                                                           const unsigned short* __restrict__ eoff16,
                                                           int2* __restrict__ csr,
                                                           const unsigned short* __restrict__ Xb,  // [N][128] bf16
                                                           const unsigned short* __restrict__ Wt1,
                                                           unsigned short* __restrict__ H,
                                                           int N, int E, int SL, int SB) {
    __shared__ char XsB[16384];   // 64 rows x 128 k bf16, XOR-swizzled
    __shared__ char WsB[32768];   // 128 n  x 128 k bf16, XOR-swizzled
    const int tid = threadIdx.x;
    if ((int)blockIdx.x < SB) {
        // slice-aligned: 2 blocks per slice, contiguous edge range; Coff16 row L2-hot
        const int j = blockIdx.x >> 1;
        const int e0 = j * SL, e1 = min(E, e0 + SL);
        const int mid = e0 + ((e1 - e0) >> 1);
        const int lo = (blockIdx.x & 1) ? mid : e0;
        const int hi = (blockIdx.x & 1) ? e1 : mid;
        const unsigned short* Crow = Coff16 + (size_t)j * N;
        for (int e = lo + tid; e < hi; e += 256) {
            int c = col[e];
            int idx = rowPtr[c] + (int)Crow[c] + (int)eoff16[e];
            csr[idx] = make_int2(row[e], __float_as_int(ew[e]));
        }
        return;
    }
    const int bm0 = ((int)blockIdx.x - SB) * 64;
    {   // stage Xb rows (bf16): 64 rows x 16 uint4; 4 uint4 per thread
        int r = tid >> 2, q4 = (tid & 3) * 4;
        const uint4* src = (const uint4*)(Xb + (size_t)min(bm0 + r, N - 1) * 128);
#pragma unroll
        for (int qq = 0; qq < 4; ++qq) {
            int kb = (q4 + qq) * 16;
            *(uint4*)(XsB + r * 256 + (kb ^ ((r & 7) << 4))) = src[q4 + qq];
        }
    }
    {   // stage Wt1 (bf16): 2048 uint4, 8 per thread
        const uint4* src = (const uint4*)Wt1;
#pragma unroll
        for (int t = 0; t < 8; ++t) {
            int i = t * 256 + tid;
            int n = i >> 4, kb = (i & 15) * 16;
            *(uint4*)(WsB + n * 256 + (kb ^ ((n & 7) << 4))) = src[i];
        }
    }
    __syncthreads();
    const int w = tid >> 6, l = tid & 63;
    const int lr = l & 15, lg = l >> 4;
    f32x4 acc[8] = {};
#pragma unroll
    for (int kk = 0; kk < 4; ++kk) {
        int r = w * 16 + lr;
        bf16x8 a = *(const bf16x8*)(XsB + r * 256 + ((kk * 64 + lg * 16) ^ ((r & 7) << 4)));
        bf16x8 b[8];
#pragma unroll
        for (int nt = 0; nt < 8; ++nt) {
            int n = nt * 16 + lr;
            b[nt] = *(const bf16x8*)(WsB + n * 256 + ((kk * 64 + lg * 16) ^ ((n & 7) << 4)));
        }
#pragma unroll
        for (int nt = 0; nt < 8; ++nt)
            acc[nt] = __builtin_amdgcn_mfma_f32_16x16x32_bf16(a, b[nt], acc[nt], 0, 0, 0);
    }
#pragma unroll
    for (int reg = 0; reg < 4; ++reg) {
        int node = bm0 + w * 16 + lg * 4 + reg;
        if (node < N) {
#pragma unroll
            for (int nt = 0; nt < 8; ++nt)
                H[(size_t)node * 128 + nt * 16 + lr] = (unsigned short)f2bf(acc[nt][reg]);
        }
    }
}

// ---- MFMA gemm2: H3[N x 64 bf16] = A(bf16 [N][128]) @ W2 ----
__global__ __launch_bounds__(256) void gemm2_mfma(const unsigned short* __restrict__ A,
                                                  const unsigned short* __restrict__ Wt2,
                                                  unsigned short* __restrict__ H, int N) {
    __shared__ char XsB[32768];   // 128 rows x 128 k bf16, swizzled
    __shared__ char WsB[16384];   // 64 n x 128 k bf16, swizzled
    const int tid = threadIdx.x;
    const int bm0 = blockIdx.x * 128;
    {   // stage A rows (bf16): 16 rows/pass, 8 passes
        int k16 = tid & 15, r0 = tid >> 4;
        for (int it = 0; it < 8; ++it) {
            int r = it * 16 + r0;
            int node = min(bm0 + r, N - 1);
            uint4 g = *(const uint4*)(A + (size_t)node * 128 + k16 * 8);
            *(uint4*)(XsB + r * 256 + ((k16 * 16) ^ ((r & 7) << 4))) = g;
        }
    }
    {   // stage Wt2: 1024 uint4
        const uint4* src = (const uint4*)Wt2;
        for (int t = 0; t < 4; ++t) {
            int i = t * 256 + tid;
            int n = i >> 4, kb = (i & 15) * 16;
            *(uint4*)(WsB + n * 256 + (kb ^ ((n & 7) << 4))) = src[i];
        }
    }
    __syncthreads();
    const int w = tid >> 6, l = tid & 63;
    const int lr = l & 15, lg = l >> 4;
    f32x4 acc[2][4] = {};
#pragma unroll
    for (int kk = 0; kk < 4; ++kk) {
        bf16x8 a[2], b[4];
#pragma unroll
        for (int mt = 0; mt < 2; ++mt) {
            int r = w * 32 + mt * 16 + lr;
            a[mt] = *(const bf16x8*)(XsB + r * 256 + ((kk * 64 + lg * 16) ^ ((r & 7) << 4)));
        }
#pragma unroll
        for (int nt = 0; nt < 4; ++nt) {
            int n = nt * 16 + lr;
            b[nt] = *(const bf16x8*)(WsB + n * 256 + ((kk * 64 + lg * 16) ^ ((n & 7) << 4)));
        }
#pragma unroll
        for (int mt = 0; mt < 2; ++mt)
#pragma unroll
            for (int nt = 0; nt < 4; ++nt)
                acc[mt][nt] = __builtin_amdgcn_mfma_f32_16x16x32_bf16(a[mt], b[nt], acc[mt][nt], 0, 0, 0);
    }
#pragma unroll
    for (int mt = 0; mt < 2; ++mt)
#pragma unroll
        for (int reg = 0; reg < 4; ++reg) {
            int node = bm0 + w * 32 + mt * 16 + lg * 4 + reg;
            if (node < N) {
#pragma unroll
                for (int nt = 0; nt < 4; ++nt)
                    H[(size_t)node * 64 + nt * 16 + lr] = (unsigned short)f2bf(acc[mt][nt][reg]);
            }
        }
}

// ---- deg from CSR segment sum; dinv = rsqrt(deg + 1). 16 lanes per node ----
__global__ __launch_bounds__(256) void deg_dinv_kernel(const int* __restrict__ rowPtr,
                                                       const int2* __restrict__ csr,
                                                       float* __restrict__ dinv, int N) {
    int idx = blockIdx.x * 256 + threadIdx.x;
    int n = idx >> 4, l = idx & 15;
    if (n >= N) return;
    int beg = rowPtr[n], end = rowPtr[n + 1];
    float s = 0.f;
    for (int i = beg + l; i < end; i += 16) s += __int_as_float(csr[i].y);
#pragma unroll
    for (int off = 8; off; off >>= 1) s += __shfl_xor(s, off, 16);
    if (l == 0) dinv[n] = rsqrtf(s + 1.0f);
}

// ---- layer 1 gather (bf16 H1) + on-fly normalize + self + bias + relu -> bf16 out ----
__global__ __launch_bounds__(256) void agg_gather1(const int* __restrict__ rowPtr,
                                                   const int2* __restrict__ csr,   // (src, raw ew)
                                                   const unsigned* __restrict__ H1u,  // [N][64] bf16x2
                                                   const float* __restrict__ dinv,
                                                   const float2* __restrict__ b2,
                                                   unsigned* __restrict__ out1, int N) {
    int n = (blockIdx.x * 256 + threadIdx.x) >> 6;
    int lane = threadIdx.x & 63;
    if (n >= N) return;
    float dn = dinv[n];
    float accx = 0.f, accy = 0.f;
    int beg = rowPtr[n], end = rowPtr[n + 1];
    int j = beg;
    for (; j + 4 <= end; j += 4) {
        int2 p0 = csr[j + 0], p1 = csr[j + 1], p2 = csr[j + 2], p3 = csr[j + 3];
        float w0 = __int_as_float(p0.y) * dinv[p0.x];
        float w1 = __int_as_float(p1.y) * dinv[p1.x];
        float w2 = __int_as_float(p2.y) * dinv[p2.x];
        float w3 = __int_as_float(p3.y) * dinv[p3.x];
        unsigned v0 = H1u[(size_t)p0.x * 64 + lane];
        unsigned v1 = H1u[(size_t)p1.x * 64 + lane];
        unsigned v2 = H1u[(size_t)p2.x * 64 + lane];
        unsigned v3 = H1u[(size_t)p3.x * 64 + lane];
        accx += w0 * bf2f(v0 & 0xffffu); accy += w0 * bf2f(v0 >> 16);
        accx += w1 * bf2f(v1 & 0xffffu); accy += w1 * bf2f(v1 >> 16);
        accx += w2 * bf2f(v2 & 0xffffu); accy += w2 * bf2f(v2 >> 16);
        accx += w3 * bf2f(v3 & 0xffffu); accy += w3 * bf2f(v3 >> 16);
    }
    for (; j < end; ++j) {
        int2 p = csr[j];
        float w = __int_as_float(p.y) * dinv[p.x];
        unsigned v = H1u[(size_t)p.x * 64 + lane];
        accx += w * bf2f(v & 0xffffu); accy += w * bf2f(v >> 16);
    }
    unsigned hv = H1u[(size_t)n * 64 + lane];
    float2 bb = b2[lane];
    float s = dn * dn;
    float ox = fmaxf(fmaf(dn, accx, s * bf2f(hv & 0xffffu)) + bb.x, 0.f);
    float oy = fmaxf(fmaf(dn, accy, s * bf2f(hv >> 16)) + bb.y, 0.f);
    out1[(size_t)n * 64 + lane] = f2bf(ox) | (f2bf(oy) << 16);
}

// ---- layer 2 gather (bf16 H3) + on-fly normalize + self + bias + L2 norm ----
__global__ __launch_bounds__(256) void agg_gather2(const int* __restrict__ rowPtr,
                                                   const int2* __restrict__ csr,
                                                   const unsigned* __restrict__ H3u,  // [N][32] bf16x2
                                                   const float* __restrict__ dinv,
                                                   const float2* __restrict__ b2,
                                                   float2* __restrict__ out2, int N) {
    int n = (blockIdx.x * 256 + threadIdx.x) >> 5;
    int l = threadIdx.x & 31;
    if (n >= N) return;
    float dn = dinv[n];
    float accx = 0.f, accy = 0.f;
    int beg = rowPtr[n], end = rowPtr[n + 1];
    int j = beg;
    for (; j + 4 <= end; j += 4) {
        int2 p0 = csr[j + 0], p1 = csr[j + 1], p2 = csr[j + 2], p3 = csr[j + 3];
        float w0 = __int_as_float(p0.y) * dinv[p0.x];
        float w1 = __int_as_float(p1.y) * dinv[p1.x];
        float w2 = __int_as_float(p2.y) * dinv[p2.x];
        float w3 = __int_as_float(p3.y) * dinv[p3.x];
        unsigned v0 = H3u[(size_t)p0.x * 32 + l];
        unsigned v1 = H3u[(size_t)p1.x * 32 + l];
        unsigned v2 = H3u[(size_t)p2.x * 32 + l];
        unsigned v3 = H3u[(size_t)p3.x * 32 + l];
        accx += w0 * bf2f(v0 & 0xffffu); accy += w0 * bf2f(v0 >> 16);
        accx += w1 * bf2f(v1 & 0xffffu); accy += w1 * bf2f(v1 >> 16);
        accx += w2 * bf2f(v2 & 0xffffu); accy += w2 * bf2f(v2 >> 16);
        accx += w3 * bf2f(v3 & 0xffffu); accy += w3 * bf2f(v3 >> 16);
    }
    for (; j < end; ++j) {
        int2 p = csr[j];
        float w = __int_as_float(p.y) * dinv[p.x];
        unsigned v = H3u[(size_t)p.x * 32 + l];
        accx += w * bf2f(v & 0xffffu); accy += w * bf2f(v >> 16);
    }
    unsigned hv = H3u[(size_t)n * 32 + l];
    float2 bb = b2[l];
    float s = dn * dn;
    float vx = fmaf(dn, accx, s * bf2f(hv & 0xffffu)) + bb.x;
    float vy = fmaf(dn, accy, s * bf2f(hv >> 16)) + bb.y;
    float ss = vx * vx + vy * vy;
#pragma unroll
    for (int off = 16; off; off >>= 1) ss += __shfl_xor(ss, off, 64);  // stays in 32-group
    float scale = 1.0f / fmaxf(sqrtf(ss), 1e-12f);
    out2[(size_t)n * 32 + l] = make_float2(vx * scale, vy * scale);
}

extern "C" void kernel_launch(void* const* d_in, const int* in_sizes, int n_in,
                              void* d_out, int out_size, void* d_ws, size_t ws_size,
                              hipStream_t stream) {
    const float* x  = (const float*)d_in[0];
    const int*   ei = (const int*)d_in[1];
    const float* ew = (const float*)d_in[2];
    const float* W1 = (const float*)d_in[3];
    const float* b1 = (const float*)d_in[4];
    const float* W2 = (const float*)d_in[5];
    const float* b2 = (const float*)d_in[6];
    float* out = (float*)d_out;
    const int N = in_sizes[0] / NF;
    const int E = in_sizes[2];
    const int* row = ei;
    const int* col = ei + E;
    const int NB = (N + 1023) / 1024;
    const int SL = (E + SLICES - 1) / SLICES;
    const int nh = (N + 1) / 2;

    char* ws = (char*)d_ws;
    size_t off = 0;
    auto take = [&](size_t bytes) {
        char* p = ws + off;
        off = (off + bytes + 255) & ~(size_t)255;
        return p;
    };
    float* dinv   = (float*)take((size_t)N * 4);
    int*   tot    = (int*)  take((size_t)N * 4);
    int*   rowPtr = (int*)  take((size_t)(N + 1) * 4);
    unsigned short* eoff16 = (unsigned short*)take((size_t)E * 2);
    int*   bsum   = (int*)  take((size_t)(NB + 1) * 4);
    unsigned short* C16    = (unsigned short*)take((size_t)SLICES * N * 2);
    int2*  csr    = (int2*) take((size_t)E * 8);
    unsigned short* Xb   = (unsigned short*)take((size_t)N * NF * 2);  // bf16 X
    unsigned short* H1   = (unsigned short*)take((size_t)N * NF * 2);  // bf16; reused as H3
    unsigned short* relu = (unsigned short*)take((size_t)N * NF * 2);  // bf16
    unsigned short* Wt1  = (unsigned short*)take(128 * 128 * 2);
    unsigned short* Wt2  = (unsigned short*)take(64 * 128 * 2);
    unsigned short* H3 = H1;   // [N][64] bf16, written after H1 consumed

    // fused prep: count_rank (LDS atomics only) || weight prep || X->bf16 cast
    const int CRB = 2 * SLICES, WTB = 96, XCB = 1024;
    prep_fused<<<CRB + WTB + XCB, 256, 0, stream>>>(col, eoff16, C16, W1, W2, Wt1, Wt2,
                                                    x, (unsigned*)Xb, N, E, SL, nh,
                                                    CRB, WTB, XCB);

    // scans -> rowPtr
    scanC_kernel<<<(N + 255) / 256, 256, 0, stream>>>(C16, tot, N);
    scan_blocks<<<NB, 256, 0, stream>>>(tot, rowPtr, bsum, N);
    scan_sums<<<1, 1, 0, stream>>>(bsum, NB);
    scan_add<<<(N + 255) / 256, 256, 0, stream>>>(rowPtr, bsum, N, NB);

    // fused: slice-aligned CSR scatter || MFMA GEMM1 (bf16 in/out)
    const int SB = 2 * SLICES;
    const int GB = (N + 63) / 64;
    scatter_gemm1_fused<<<SB + GB, 256, 0, stream>>>(row, col, ew, rowPtr, C16, eoff16,
                                                     csr, Xb, Wt1, H1, N, E, SL, SB);

    // degree -> dinv (weights normalized on the fly in agg kernels)
    deg_dinv_kernel<<<(N * 16 + 255) / 256, 256, 0, stream>>>(rowPtr, csr, dinv, N);

    // layer 1 aggregation + bias + relu -> bf16
    agg_gather1<<<(N * 64 + 255) / 256, 256, 0, stream>>>(rowPtr, csr, (const unsigned*)H1,
                                                          dinv, (const float2*)b1,
                                                          (unsigned*)relu, N);

    // layer 2: MFMA GEMM ; gather + bias + l2norm
    gemm2_mfma<<<(N + 127) / 128, 256, 0, stream>>>(relu, Wt2, H3, N);
    agg_gather2<<<(N * 32 + 255) / 256, 256, 0, stream>>>(rowPtr, csr, (const unsigned*)H3,
                                                          dinv, (const float2*)b2,
                                                          (float2*)out, N);
}

// Round 10
// 149.426 us; speedup vs baseline: 1.3660x; 1.0722x over previous
//
#include <hip/hip_runtime.h>

#define NF 128   // in/hidden features
#define NC 64    // classes
#define SLICES 64

typedef short bf16x8 __attribute__((ext_vector_type(8)));
typedef float f32x4 __attribute__((ext_vector_type(4)));

__device__ __forceinline__ unsigned f2bf(float f) {   // fp32 -> bf16 (RTN)
    unsigned u = __float_as_uint(f);
    return (u + 0x7FFFu + ((u >> 16) & 1u)) >> 16;
}
__device__ __forceinline__ float bf2f(unsigned h) { return __uint_as_float(h << 16); }

// ---- fused prep: count_rank blocks + weight-transpose blocks + X->bf16 cast blocks ----
__global__ __launch_bounds__(256) void prep_fused(const int* __restrict__ col,
                                                  unsigned short* __restrict__ eoff16,
                                                  unsigned short* __restrict__ C16,
                                                  const float* __restrict__ W1,
                                                  const float* __restrict__ W2,
                                                  unsigned short* __restrict__ Wt1,
                                                  unsigned short* __restrict__ Wt2,
                                                  const float* __restrict__ X,
                                                  unsigned* __restrict__ Xb2,   // [N*64] bf16x2
                                                  int N, int E, int SL, int nh,
                                                  int CRB, int WTB, int XCB) {
    __shared__ unsigned hist[12544];
    const int b = blockIdx.x;
    const int tid = threadIdx.x;
    if (b < CRB) {
        // ---- count + rank (LDS-private histogram, 2 packed 16-bit counters/word) ----
        const int j = b >> 1;
        const int h = b & 1;
        const int nlo = h * nh;
        const int nhi = min(N, nlo + nh);
        const int words = (nhi - nlo + 1) >> 1;
        for (int i = tid; i < words; i += 256) hist[i] = 0;
        __syncthreads();
        const int e0 = j * SL, e1 = min(E, e0 + SL);
        for (int e = e0 + tid; e < e1; e += 256) {
            int c = col[e];
            if (c >= nlo && c < nhi) {
                int cl = c - nlo;
                unsigned sh = (cl & 1) * 16;
                unsigned old = atomicAdd(&hist[cl >> 1], 1u << sh);
                eoff16[e] = (unsigned short)((old >> sh) & 0xffffu);
            }
        }
        __syncthreads();
        unsigned* Cw = (unsigned*)(C16 + (size_t)j * N + nlo);
        for (int i = tid; i < words; i += 256) Cw[i] = hist[i];
    } else if (b < CRB + WTB) {
        // ---- weight transpose + bf16 cast ----
        int i = (b - CRB) * 256 + tid;
        if (i < 128 * 128) {
            int k = i >> 7, n = i & 127;
            Wt1[n * 128 + k] = (unsigned short)f2bf(W1[i]);
        } else {
            int j = i - 128 * 128;
            if (j < 128 * 64) {
                int k = j >> 6, n = j & 63;
                Wt2[n * 128 + k] = (unsigned short)f2bf(W2[j]);
            }
        }
    } else {
        // ---- X -> bf16 streaming cast ----
        const float4* X4 = (const float4*)X;
        uint2* O = (uint2*)Xb2;
        int items = N * 32;
        for (int i = (b - CRB - WTB) * 256 + tid; i < items; i += XCB * 256) {
            float4 v = X4[i];
            O[i] = make_uint2(f2bf(v.x) | (f2bf(v.y) << 16),
                              f2bf(v.z) | (f2bf(v.w) << 16));
        }
    }
}

// ---- per-node exclusive scan over slices (in place) + totals ----
__global__ __launch_bounds__(256) void scanC_kernel(unsigned short* __restrict__ C16,
                                                    int* __restrict__ tot, int N) {
    int n = blockIdx.x * 256 + threadIdx.x;
    if (n >= N) return;
    int t = 0;
#pragma unroll 4
    for (int j = 0; j < SLICES; ++j) {
        size_t idx = (size_t)j * N + n;
        int v = C16[idx];
        C16[idx] = (unsigned short)t;
        t += v;
    }
    tot[n] = t;
}

// ---- exclusive scan of tot[N] -> rowPtr[N+1] ----
__global__ __launch_bounds__(256) void scan_blocks(const int* __restrict__ cnt,
                                                   int* __restrict__ excl,
                                                   int* __restrict__ bsum, int N) {
    __shared__ int sh[256];
    int t = threadIdx.x;
    int base = blockIdx.x * 1024 + t * 4;
    int v0 = base + 0 < N ? cnt[base + 0] : 0;
    int v1 = base + 1 < N ? cnt[base + 1] : 0;
    int v2 = base + 2 < N ? cnt[base + 2] : 0;
    int v3 = base + 3 < N ? cnt[base + 3] : 0;
    int s = v0 + v1 + v2 + v3;
    sh[t] = s;
    __syncthreads();
    for (int off = 1; off < 256; off <<= 1) {
        int x = (t >= off) ? sh[t - off] : 0;
        __syncthreads();
        sh[t] += x;
        __syncthreads();
    }
    int incl = sh[t];
    int exclT = incl - s;
    if (t == 255) bsum[blockIdx.x] = incl;
    if (base + 0 < N) excl[base + 0] = exclT;
    if (base + 1 < N) excl[base + 1] = exclT + v0;
    if (base + 2 < N) excl[base + 2] = exclT + v0 + v1;
    if (base + 3 < N) excl[base + 3] = exclT + v0 + v1 + v2;
}

__global__ void scan_sums(int* __restrict__ bsum, int nb) {
    int run = 0;
    for (int i = 0; i < nb; ++i) { int v = bsum[i]; bsum[i] = run; run += v; }
    bsum[nb] = run;
}

__global__ __launch_bounds__(256) void scan_add(int* __restrict__ excl,
                                                const int* __restrict__ bsum,
                                                int N, int nb) {
    int i = blockIdx.x * 256 + threadIdx.x;
    if (i < N) excl[i] += bsum[i >> 10];
    if (i == 0) excl[N] = bsum[nb];
}

// ---- fused: slice-aligned scatter (packed 4B entries, no atomics) + MFMA gemm1 ----
__global__ __launch_bounds__(256) void scatter_gemm1_fused(const int* __restrict__ row,
                                                           const int* __restrict__ col,
                                                           const float* __restrict__ ew,
                                                           const int* __restrict__ rowPtr,
                                                           const unsigned short* __restrict__ Coff16,
                                                           const unsigned short* __restrict__ eoff16,
                                                           unsigned* __restrict__ csru,
                                                           const unsigned short* __restrict__ Xb,  // [N][128] bf16
                                                           const unsigned short* __restrict__ Wt1,
                                                           unsigned short* __restrict__ H,
                                                           int N, int E, int SL, int SB) {
    __shared__ char XsB[16384];   // 64 rows x 128 k bf16, XOR-swizzled
    __shared__ char WsB[32768];   // 128 n  x 128 k bf16, XOR-swizzled
    const int tid = threadIdx.x;
    if ((int)blockIdx.x < SB) {
        // 8 blocks per slice, contiguous edge chunks; Coff16 row stays L2-hot
        const int j = blockIdx.x >> 3;
        const int sub = blockIdx.x & 7;
        const int e0 = j * SL, e1 = min(E, e0 + SL);
        const int per = ((e1 - e0) + 7) >> 3;
        const int lo = min(e1, e0 + sub * per);
        const int hi = min(e1, lo + per);
        const unsigned short* Crow = Coff16 + (size_t)j * N;
        for (int e = lo + tid; e < hi; e += 256) {
            int c = col[e];
            int idx = rowPtr[c] + (int)Crow[c] + (int)eoff16[e];
            csru[idx] = ((unsigned)row[e] << 16) | f2bf(ew[e]);
        }
        return;
    }
    const int bm0 = ((int)blockIdx.x - SB) * 64;
    {   // stage Xb rows (bf16): 64 rows x 16 uint4; 4 uint4 per thread
        int r = tid >> 2, q4 = (tid & 3) * 4;
        const uint4* src = (const uint4*)(Xb + (size_t)min(bm0 + r, N - 1) * 128);
#pragma unroll
        for (int qq = 0; qq < 4; ++qq) {
            int kb = (q4 + qq) * 16;
            *(uint4*)(XsB + r * 256 + (kb ^ ((r & 7) << 4))) = src[q4 + qq];
        }
    }
    {   // stage Wt1 (bf16): 2048 uint4, 8 per thread
        const uint4* src = (const uint4*)Wt1;
#pragma unroll
        for (int t = 0; t < 8; ++t) {
            int i = t * 256 + tid;
            int n = i >> 4, kb = (i & 15) * 16;
            *(uint4*)(WsB + n * 256 + (kb ^ ((n & 7) << 4))) = src[i];
        }
    }
    __syncthreads();
    const int w = tid >> 6, l = tid & 63;
    const int lr = l & 15, lg = l >> 4;
    f32x4 acc[8] = {};
#pragma unroll
    for (int kk = 0; kk < 4; ++kk) {
        int r = w * 16 + lr;
        bf16x8 a = *(const bf16x8*)(XsB + r * 256 + ((kk * 64 + lg * 16) ^ ((r & 7) << 4)));
        bf16x8 b[8];
#pragma unroll
        for (int nt = 0; nt < 8; ++nt) {
            int n = nt * 16 + lr;
            b[nt] = *(const bf16x8*)(WsB + n * 256 + ((kk * 64 + lg * 16) ^ ((n & 7) << 4)));
        }
#pragma unroll
        for (int nt = 0; nt < 8; ++nt)
            acc[nt] = __builtin_amdgcn_mfma_f32_16x16x32_bf16(a, b[nt], acc[nt], 0, 0, 0);
    }
#pragma unroll
    for (int reg = 0; reg < 4; ++reg) {
        int node = bm0 + w * 16 + lg * 4 + reg;
        if (node < N) {
#pragma unroll
            for (int nt = 0; nt < 8; ++nt)
                H[(size_t)node * 128 + nt * 16 + lr] = (unsigned short)f2bf(acc[nt][reg]);
        }
    }
}

// ---- MFMA gemm2: H3[N x 64 bf16] = A(bf16 [N][128]) @ W2 ----
__global__ __launch_bounds__(256) void gemm2_mfma(const unsigned short* __restrict__ A,
                                                  const unsigned short* __restrict__ Wt2,
                                                  unsigned short* __restrict__ H, int N) {
    __shared__ char XsB[32768];   // 128 rows x 128 k bf16, swizzled
    __shared__ char WsB[16384];   // 64 n x 128 k bf16, swizzled
    const int tid = threadIdx.x;
    const int bm0 = blockIdx.x * 128;
    {   // stage A rows (bf16): 16 rows/pass, 8 passes
        int k16 = tid & 15, r0 = tid >> 4;
        for (int it = 0; it < 8; ++it) {
            int r = it * 16 + r0;
            int node = min(bm0 + r, N - 1);
            uint4 g = *(const uint4*)(A + (size_t)node * 128 + k16 * 8);
            *(uint4*)(XsB + r * 256 + ((k16 * 16) ^ ((r & 7) << 4))) = g;
        }
    }
    {   // stage Wt2: 1024 uint4
        const uint4* src = (const uint4*)Wt2;
        for (int t = 0; t < 4; ++t) {
            int i = t * 256 + tid;
            int n = i >> 4, kb = (i & 15) * 16;
            *(uint4*)(WsB + n * 256 + (kb ^ ((n & 7) << 4))) = src[i];
        }
    }
    __syncthreads();
    const int w = tid >> 6, l = tid & 63;
    const int lr = l & 15, lg = l >> 4;
    f32x4 acc[2][4] = {};
#pragma unroll
    for (int kk = 0; kk < 4; ++kk) {
        bf16x8 a[2], b[4];
#pragma unroll
        for (int mt = 0; mt < 2; ++mt) {
            int r = w * 32 + mt * 16 + lr;
            a[mt] = *(const bf16x8*)(XsB + r * 256 + ((kk * 64 + lg * 16) ^ ((r & 7) << 4)));
        }
#pragma unroll
        for (int nt = 0; nt < 4; ++nt) {
            int n = nt * 16 + lr;
            b[nt] = *(const bf16x8*)(WsB + n * 256 + ((kk * 64 + lg * 16) ^ ((n & 7) << 4)));
        }
#pragma unroll
        for (int mt = 0; mt < 2; ++mt)
#pragma unroll
            for (int nt = 0; nt < 4; ++nt)
                acc[mt][nt] = __builtin_amdgcn_mfma_f32_16x16x32_bf16(a[mt], b[nt], acc[mt][nt], 0, 0, 0);
    }
#pragma unroll
    for (int mt = 0; mt < 2; ++mt)
#pragma unroll
        for (int reg = 0; reg < 4; ++reg) {
            int node = bm0 + w * 32 + mt * 16 + lg * 4 + reg;
            if (node < N) {
#pragma unroll
                for (int nt = 0; nt < 4; ++nt)
                    H[(size_t)node * 64 + nt * 16 + lr] = (unsigned short)f2bf(acc[mt][nt][reg]);
            }
        }
}

// ---- deg from CSR segment sum; dinv = rsqrt(deg + 1). 16 lanes per node ----
__global__ __launch_bounds__(256) void deg_dinv_kernel(const int* __restrict__ rowPtr,
                                                       const unsigned* __restrict__ csru,
                                                       float* __restrict__ dinv, int N) {
    int idx = blockIdx.x * 256 + threadIdx.x;
    int n = idx >> 4, l = idx & 15;
    if (n >= N) return;
    int beg = rowPtr[n], end = rowPtr[n + 1];
    float s = 0.f;
    for (int i = beg + l; i < end; i += 16) s += bf2f(csru[i] & 0xffffu);
#pragma unroll
    for (int off = 8; off; off >>= 1) s += __shfl_xor(s, off, 16);
    if (l == 0) dinv[n] = rsqrtf(s + 1.0f);
}

// ---- layer 1 gather (bf16 H1, packed 4B csr) + self + bias + relu -> bf16 out ----
__global__ __launch_bounds__(256) void agg_gather1(const int* __restrict__ rowPtr,
                                                   const unsigned* __restrict__ csru,
                                                   const unsigned* __restrict__ H1u,  // [N][64] bf16x2
                                                   const float* __restrict__ dinv,
                                                   const float2* __restrict__ b2,
                                                   unsigned* __restrict__ out1, int N) {
    int n = (blockIdx.x * 256 + threadIdx.x) >> 6;
    int lane = threadIdx.x & 63;
    if (n >= N) return;
    float dn = dinv[n];
    float accx = 0.f, accy = 0.f;
    int beg = rowPtr[n], end = rowPtr[n + 1];
    int j = beg;
    for (; j + 4 <= end; j += 4) {
        unsigned p0 = csru[j + 0], p1 = csru[j + 1], p2 = csru[j + 2], p3 = csru[j + 3];
        int s0 = p0 >> 16, s1 = p1 >> 16, s2 = p2 >> 16, s3 = p3 >> 16;
        float w0 = bf2f(p0 & 0xffffu) * dinv[s0];
        float w1 = bf2f(p1 & 0xffffu) * dinv[s1];
        float w2 = bf2f(p2 & 0xffffu) * dinv[s2];
        float w3 = bf2f(p3 & 0xffffu) * dinv[s3];
        unsigned v0 = H1u[(size_t)s0 * 64 + lane];
        unsigned v1 = H1u[(size_t)s1 * 64 + lane];
        unsigned v2 = H1u[(size_t)s2 * 64 + lane];
        unsigned v3 = H1u[(size_t)s3 * 64 + lane];
        accx += w0 * bf2f(v0 & 0xffffu); accy += w0 * bf2f(v0 >> 16);
        accx += w1 * bf2f(v1 & 0xffffu); accy += w1 * bf2f(v1 >> 16);
        accx += w2 * bf2f(v2 & 0xffffu); accy += w2 * bf2f(v2 >> 16);
        accx += w3 * bf2f(v3 & 0xffffu); accy += w3 * bf2f(v3 >> 16);
    }
    for (; j < end; ++j) {
        unsigned p = csru[j];
        int s0 = p >> 16;
        float w = bf2f(p & 0xffffu) * dinv[s0];
        unsigned v = H1u[(size_t)s0 * 64 + lane];
        accx += w * bf2f(v & 0xffffu); accy += w * bf2f(v >> 16);
    }
    unsigned hv = H1u[(size_t)n * 64 + lane];
    float2 bb = b2[lane];
    float s = dn * dn;
    float ox = fmaxf(fmaf(dn, accx, s * bf2f(hv & 0xffffu)) + bb.x, 0.f);
    float oy = fmaxf(fmaf(dn, accy, s * bf2f(hv >> 16)) + bb.y, 0.f);
    out1[(size_t)n * 64 + lane] = f2bf(ox) | (f2bf(oy) << 16);
}

// ---- layer 2 gather (bf16 H3, packed csr) + self + bias + L2 norm ----
__global__ __launch_bounds__(256) void agg_gather2(const int* __restrict__ rowPtr,
                                                   const unsigned* __restrict__ csru,
                                                   const unsigned* __restrict__ H3u,  // [N][32] bf16x2
                                                   const float* __restrict__ dinv,
                                                   const float2* __restrict__ b2,
                                                   float2* __restrict__ out2, int N) {
    int n = (blockIdx.x * 256 + threadIdx.x) >> 5;
    int l = threadIdx.x & 31;
    if (n >= N) return;
    float dn = dinv[n];
    float accx = 0.f, accy = 0.f;
    int beg = rowPtr[n], end = rowPtr[n + 1];
    int j = beg;
    for (; j + 4 <= end; j += 4) {
        unsigned p0 = csru[j + 0], p1 = csru[j + 1], p2 = csru[j + 2], p3 = csru[j + 3];
        int s0 = p0 >> 16, s1 = p1 >> 16, s2 = p2 >> 16, s3 = p3 >> 16;
        float w0 = bf2f(p0 & 0xffffu) * dinv[s0];
        float w1 = bf2f(p1 & 0xffffu) * dinv[s1];
        float w2 = bf2f(p2 & 0xffffu) * dinv[s2];
        float w3 = bf2f(p3 & 0xffffu) * dinv[s3];
        unsigned v0 = H3u[(size_t)s0 * 32 + l];
        unsigned v1 = H3u[(size_t)s1 * 32 + l];
        unsigned v2 = H3u[(size_t)s2 * 32 + l];
        unsigned v3 = H3u[(size_t)s3 * 32 + l];
        accx += w0 * bf2f(v0 & 0xffffu); accy += w0 * bf2f(v0 >> 16);
        accx += w1 * bf2f(v1 & 0xffffu); accy += w1 * bf2f(v1 >> 16);
        accx += w2 * bf2f(v2 & 0xffffu); accy += w2 * bf2f(v2 >> 16);
        accx += w3 * bf2f(v3 & 0xffffu); accy += w3 * bf2f(v3 >> 16);
    }
    for (; j < end; ++j) {
        unsigned p = csru[j];
        int s0 = p >> 16;
        float w = bf2f(p & 0xffffu) * dinv[s0];
        unsigned v = H3u[(size_t)s0 * 32 + l];
        accx += w * bf2f(v & 0xffffu); accy += w * bf2f(v >> 16);
    }
    unsigned hv = H3u[(size_t)n * 32 + l];
    float2 bb = b2[l];
    float s = dn * dn;
    float vx = fmaf(dn, accx, s * bf2f(hv & 0xffffu)) + bb.x;
    float vy = fmaf(dn, accy, s * bf2f(hv >> 16)) + bb.y;
    float ss = vx * vx + vy * vy;
#pragma unroll
    for (int off = 16; off; off >>= 1) ss += __shfl_xor(ss, off, 64);  // stays in 32-group
    float scale = 1.0f / fmaxf(sqrtf(ss), 1e-12f);
    out2[(size_t)n * 32 + l] = make_float2(vx * scale, vy * scale);
}

extern "C" void kernel_launch(void* const* d_in, const int* in_sizes, int n_in,
                              void* d_out, int out_size, void* d_ws, size_t ws_size,
                              hipStream_t stream) {
    const float* x  = (const float*)d_in[0];
    const int*   ei = (const int*)d_in[1];
    const float* ew = (const float*)d_in[2];
    const float* W1 = (const float*)d_in[3];
    const float* b1 = (const float*)d_in[4];
    const float* W2 = (const float*)d_in[5];
    const float* b2 = (const float*)d_in[6];
    float* out = (float*)d_out;
    const int N = in_sizes[0] / NF;
    const int E = in_sizes[2];
    const int* row = ei;
    const int* col = ei + E;
    const int NB = (N + 1023) / 1024;
    const int SL = (E + SLICES - 1) / SLICES;
    const int nh = (N + 1) / 2;

    char* ws = (char*)d_ws;
    size_t off = 0;
    auto take = [&](size_t bytes) {
        char* p = ws + off;
        off = (off + bytes + 255) & ~(size_t)255;
        return p;
    };
    float* dinv   = (float*)take((size_t)N * 4);
    int*   tot    = (int*)  take((size_t)N * 4);
    int*   rowPtr = (int*)  take((size_t)(N + 1) * 4);
    unsigned short* eoff16 = (unsigned short*)take((size_t)E * 2);
    int*   bsum   = (int*)  take((size_t)(NB + 1) * 4);
    unsigned short* C16    = (unsigned short*)take((size_t)SLICES * N * 2);
    unsigned* csru = (unsigned*)take((size_t)E * 4);
    unsigned short* Xb   = (unsigned short*)take((size_t)N * NF * 2);  // bf16 X
    unsigned short* H1   = (unsigned short*)take((size_t)N * NF * 2);  // bf16; reused as H3
    unsigned short* relu = (unsigned short*)take((size_t)N * NF * 2);  // bf16
    unsigned short* Wt1  = (unsigned short*)take(128 * 128 * 2);
    unsigned short* Wt2  = (unsigned short*)take(64 * 128 * 2);
    unsigned short* H3 = H1;   // [N][64] bf16, written after H1 consumed

    // fused prep: count_rank (LDS atomics only) || weight prep || X->bf16 cast
    const int CRB = 2 * SLICES, WTB = 96, XCB = 1024;
    prep_fused<<<CRB + WTB + XCB, 256, 0, stream>>>(col, eoff16, C16, W1, W2, Wt1, Wt2,
                                                    x, (unsigned*)Xb, N, E, SL, nh,
                                                    CRB, WTB, XCB);

    // scans -> rowPtr
    scanC_kernel<<<(N + 255) / 256, 256, 0, stream>>>(C16, tot, N);
    scan_blocks<<<NB, 256, 0, stream>>>(tot, rowPtr, bsum, N);
    scan_sums<<<1, 1, 0, stream>>>(bsum, NB);
    scan_add<<<(N + 255) / 256, 256, 0, stream>>>(rowPtr, bsum, N, NB);

    // fused: slice-aligned CSR scatter (4B packed) || MFMA GEMM1 (bf16 in/out)
    const int SB = 8 * SLICES;
    const int GB = (N + 63) / 64;
    scatter_gemm1_fused<<<SB + GB, 256, 0, stream>>>(row, col, ew, rowPtr, C16, eoff16,
                                                     csru, Xb, Wt1, H1, N, E, SL, SB);

    // degree -> dinv (weights normalized on the fly in agg kernels)
    deg_dinv_kernel<<<(N * 16 + 255) / 256, 256, 0, stream>>>(rowPtr, csru, dinv, N);

    // layer 1 aggregation + bias + relu -> bf16
    agg_gather1<<<(N * 64 + 255) / 256, 256, 0, stream>>>(rowPtr, csru, (const unsigned*)H1,
                                                          dinv, (const float2*)b1,
                                                          (unsigned*)relu, N);

    // layer 2: MFMA GEMM ; gather + bias + l2norm
    gemm2_mfma<<<(N + 127) / 128, 256, 0, stream>>>(relu, Wt2, H3, N);
    agg_gather2<<<(N * 32 + 255) / 256, 256, 0, stream>>>(rowPtr, csru, (const unsigned*)H3,
                                                          dinv, (const float2*)b2,
                                                          (float2*)out, N);
}